// Round 9
// baseline (54.061 us; speedup 1.0000x reference)
//
#include <hip/hip_runtime.h>
#include <cfloat>

typedef float f32x16 __attribute__((ext_vector_type(16)));
typedef short s16x8  __attribute__((ext_vector_type(8)));

// Problem constants
constexpr int B = 4, N = 8192;
constexpr int IB   = 4;              // 32-row i-blocks per wave (rows = minimized-over side)
constexpr int JT   = 8;              // 32-col j-tiles per wave (cols = output side)
constexpr int ISTR = N / (32 * IB);  // 64 i-strips
constexpr int JSTR = N / (32 * JT);  // 32 j-strips
constexpr int NSEG = 2 * B;          // 8 (dir,b) segments

__device__ __forceinline__ unsigned short f2bf(float x) {   // RNE bf16
    unsigned int u = __float_as_uint(x);
    u += 0x7fffu + ((u >> 16) & 1u);
    return (unsigned short)(u >> 16);
}
__device__ __forceinline__ float bf2f(unsigned short h) {
    return __uint_as_float((unsigned int)h << 16);
}

// Pack BOTH clouds in BOTH operand forms (validated slot plan, R7/R8):
//   A-form row: [-2xh,-2yh,-2zh, -2xl,-2yl,-2zl, -2xh,-2yh | -2zh, 1, 1, nh, nl, 0,0,0]
//   B-form col: [  xh,  yh,  zh,   xh,  yh,  zh,   xl,  yl |   zl, nh, nl, 1, 1, 0,0,0]
// => MFMA c = nA + nB - 2*a.b  (full squared distance; ll term dropped, err ~1e-3)
// Fragment layout (32x32x16): lane holds (row|col)=lane&31, k = 8*(lane>>5)+kk.
__global__ __launch_bounds__(256) void pack_kernel(
        const float* __restrict__ pred, const float* __restrict__ gt,
        uint4* __restrict__ Aform, uint4* __restrict__ Bform) {
    int id    = blockIdx.x * 256 + threadIdx.x;  // [0, 262144)
    int form  = id >> 17;                        // 0 = A-form, 1 = B-form
    int cloud = (id >> 16) & 1;                  // 0 = pred, 1 = gt
    int rem   = id & 65535;
    int b     = rem >> 14;
    int t2    = rem & 16383;
    int blk   = t2 >> 6;                         // 32-point block [0,256)
    int lane  = t2 & 63;
    int h     = lane >> 5;
    int row   = blk * 32 + (lane & 31);

    const float* s = (cloud ? gt : pred) + ((size_t)b * N + row) * 3;
    float x = s[0], y = s[1], z = s[2];
    unsigned short xh = f2bf(x), yh = f2bf(y), zh = f2bf(z);
    float xl = x - bf2f(xh), yl = y - bf2f(yh), zl = z - bf2f(zh);
    float n = fmaf(x, x, fmaf(y, y, z * z));
    unsigned short nh = f2bf(n);
    unsigned short nl = f2bf(n - bf2f(nh));
    const unsigned short ONE = 0x3F80;

    unsigned short w[8];
    if (form == 0) {   // A-form: -2 folded in
        unsigned short mxh = f2bf(-2.f * bf2f(xh));
        unsigned short myh = f2bf(-2.f * bf2f(yh));
        unsigned short mzh = f2bf(-2.f * bf2f(zh));
        if (h == 0) {
            w[0] = mxh; w[1] = myh; w[2] = mzh;
            w[3] = f2bf(-2.f * xl); w[4] = f2bf(-2.f * yl); w[5] = f2bf(-2.f * zl);
            w[6] = mxh; w[7] = myh;
        } else {
            w[0] = mzh; w[1] = ONE; w[2] = ONE; w[3] = nh; w[4] = nl;
            w[5] = 0; w[6] = 0; w[7] = 0;
        }
    } else {           // B-form
        if (h == 0) {
            w[0] = xh; w[1] = yh; w[2] = zh;
            w[3] = xh; w[4] = yh; w[5] = zh;
            w[6] = f2bf(xl); w[7] = f2bf(yl);
        } else {
            w[0] = f2bf(zl); w[1] = nh; w[2] = nl; w[3] = ONE; w[4] = ONE;
            w[5] = 0; w[6] = 0; w[7] = 0;
        }
    }
    uint4 out;
    out.x = (unsigned)w[0] | ((unsigned)w[1] << 16);
    out.y = (unsigned)w[2] | ((unsigned)w[3] << 16);
    out.z = (unsigned)w[4] | ((unsigned)w[5] << 16);
    out.w = (unsigned)w[6] | ((unsigned)w[7] << 16);
    (form ? Bform : Aform)[(((size_t)cloud * B + b) * 256 + blk) * 64 + lane] = out;
}

// Both directions use ONLY the cheap col-min path (tree over 16 regs +
// shfl_xor(32)): dir 0 minimizes over pred rows (per-gt mins), dir 1 swaps
// operands so pred becomes the col side. No LDS, no barriers, no row path.
__global__ __launch_bounds__(256) void chamfer_mfma(
        const uint4* __restrict__ Aform, const uint4* __restrict__ Bform,
        unsigned short* __restrict__ part) {
    int wave = blockIdx.x * 4 + (threadIdx.x >> 6);
    int lane = threadIdx.x & 63;
    int js   = wave & (JSTR - 1);
    int r    = wave / JSTR;
    int is   = r & (ISTR - 1);
    r /= ISTR;
    int b    = r & (B - 1);
    int dir  = r / B;                 // 0: rows=pred -> per-gt mins; 1: rows=gt
    int Acl  = dir;                   // dir0: A=pred(0)?? see below
    // dir 0: minimize over pred => A-side cloud = pred(0), B-side = gt(1)
    // dir 1: minimize over gt   => A-side cloud = gt(1),  B-side = pred(0)
    Acl = dir ? 1 : 0;
    int Bcl = 1 - Acl;

    s16x8 afr[IB];
#pragma unroll
    for (int ib = 0; ib < IB; ++ib)
        afr[ib] = __builtin_bit_cast(s16x8,
            Aform[(((size_t)Acl * B + b) * 256 + is * IB + ib) * 64 + lane]);

    const uint4* bbase = Bform + (((size_t)Bcl * B + b) * 256 + js * JT) * 64 + lane;
    unsigned short* po = part + (((size_t)dir * B + b) * ISTR + is) * N + js * JT * 32;

    uint4 braw = bbase[0];
#pragma unroll
    for (int jt = 0; jt < JT; ++jt) {
        s16x8 bfr = __builtin_bit_cast(s16x8, braw);
        if (jt + 1 < JT) braw = bbase[(size_t)(jt + 1) * 64];
        float acc = FLT_MAX;
#pragma unroll
        for (int ib = 0; ib < IB; ++ib) {
            f32x16 zc = {};
            f32x16 c = __builtin_amdgcn_mfma_f32_32x32x16_bf16(afr[ib], bfr, zc, 0, 0, 0);
            // col-min tree over this lane's 16 rows (v_min3 fusion)
            float u0 = fminf(fminf(c[0], c[1]), c[2]);
            float u1 = fminf(fminf(c[3], c[4]), c[5]);
            float u2 = fminf(fminf(c[6], c[7]), c[8]);
            float u3 = fminf(fminf(c[9], c[10]), c[11]);
            float u4 = fminf(fminf(c[12], c[13]), c[14]);
            float m  = fminf(fminf(u0, u1),
                             fminf(fminf(u2, u3), fminf(u4, c[15])));
            acc = fminf(acc, m);
        }
        // other 16 rows of this col live in lane^32
        float colmin = fminf(acc, __shfl_xor(acc, 32));
        if (lane < 32)
            po[jt * 32 + lane] = f2bf(colmin);
    }
}

// 256 blocks: seg = (dir,b); min over 64 i-strips, then block sum/max partials.
__global__ __launch_bounds__(256) void reduce1(
        const unsigned short* __restrict__ part,
        float* __restrict__ bsum, float* __restrict__ bmax) {
    int bk  = blockIdx.x;
    int seg = bk >> 5;                 // 0..7
    int idx = (bk & 31) * 256 + threadIdx.x;
    const unsigned short* base = part + (size_t)seg * ISTR * N + idx;
    float v = FLT_MAX;
#pragma unroll 8
    for (int s = 0; s < ISTR; ++s)
        v = fminf(v, bf2f(base[(size_t)s * N]));
    __shared__ float ssum[256], smax[256];
    ssum[threadIdx.x] = v;
    smax[threadIdx.x] = v;
    __syncthreads();
    for (int st = 128; st > 0; st >>= 1) {
        if (threadIdx.x < st) {
            ssum[threadIdx.x] += ssum[threadIdx.x + st];
            smax[threadIdx.x] = fmaxf(smax[threadIdx.x], smax[threadIdx.x + st]);
        }
        __syncthreads();
    }
    if (threadIdx.x == 0) { bsum[bk] = ssum[0]; bmax[bk] = smax[0]; }
}

// Combine 256 block partials. Blocks [seg*32, seg*32+32) belong to segment seg.
__global__ __launch_bounds__(256) void final_combine(
        const float* __restrict__ bsum, const float* __restrict__ bmax,
        float* __restrict__ out) {
    int t = threadIdx.x;
    __shared__ float ss[256], sm[256];
    ss[t] = bsum[t];
    sm[t] = bmax[t];
    __syncthreads();
    for (int st = 128; st > 0; st >>= 1) {
        if (t < st) ss[t] += ss[t + st];
        __syncthreads();
    }
    for (int st = 16; st > 0; st >>= 1) {
        if ((t & 31) < st) sm[t] = fmaxf(sm[t], sm[t + st]);
        __syncthreads();
    }
    if (t == 0) {
        float hsum = 0.f;
#pragma unroll
        for (int k = 0; k < NSEG; ++k) hsum += sm[k * 32];
        out[0] = ss[0] / (float)(B * N);   // chamfer
        out[1] = hsum / (float)B;          // hausdorff
    }
}

extern "C" void kernel_launch(void* const* d_in, const int* in_sizes, int n_in,
                              void* d_out, int out_size, void* d_ws, size_t ws_size,
                              hipStream_t stream) {
    const float* pred = (const float*)d_in[0];
    const float* gt   = (const float*)d_in[1];
    float* out = (float*)d_out;

    char* p = (char*)d_ws;
    uint4* Aform = (uint4*)p;  p += (size_t)2 * B * 256 * 64 * 16;   // 2 MB
    uint4* Bform = (uint4*)p;  p += (size_t)2 * B * 256 * 64 * 16;   // 2 MB
    unsigned short* part = (unsigned short*)p;
    p += (size_t)2 * B * ISTR * N * 2;                               // 8 MB
    float* bsum = (float*)p;   p += 256 * 4;
    float* bmax = (float*)p;

    pack_kernel<<<1024, 256, 0, stream>>>(pred, gt, Aform, Bform);
    // waves: dir(2) x b(4) x is(64) x js(32) = 16384 -> 4096 blocks x 4 waves
    chamfer_mfma<<<4096, 256, 0, stream>>>(Aform, Bform, part);
    reduce1<<<256, 256, 0, stream>>>(part, bsum, bmax);
    final_combine<<<1, 256, 0, stream>>>(bsum, bmax, out);
}